// Round 1
// 294.496 us; speedup vs baseline: 1.0394x; 1.0394x over previous
//
#include <hip/hip_runtime.h>

#define B_ 16
#define D_ 128
#define L_ 8192
#define M_ 128
#define NCHUNK 32
#define LT 256
#define SL 64
#define PHI_SCALE 0.08838834764831845f

typedef unsigned short ushort_t;
typedef ushort_t ushort8 __attribute__((ext_vector_type(8)));
typedef ushort_t ushort4v __attribute__((ext_vector_type(4)));
typedef float float4v __attribute__((ext_vector_type(4)));
typedef __bf16 bf16x8 __attribute__((ext_vector_type(8)));

__device__ __forceinline__ ushort_t f2bf(float f) {
    unsigned int u = __builtin_bit_cast(unsigned int, f);
    unsigned int r = u + 0x7FFFu + ((u >> 16) & 1u);   // RTNE
    return (ushort_t)(r >> 16);
}

__device__ __forceinline__ float4v mfma16(ushort8 a, ushort8 b, float4v c) {
    return __builtin_amdgcn_mfma_f32_16x16x32_bf16(
        __builtin_bit_cast(bf16x8, a), __builtin_bit_cast(bf16x8, b), c, 0, 0, 0);
}

// Stage F (D x M) into LDS as GEMM B-fragment layout: blocks [kt 0..3][nt 0..7][lane64][j 0..7]
// B[k=d][n=m], lane = qb*16+cb -> k = kt*32+qb*8+j, m = nt*16+cb
__device__ __forceinline__ void stage_features(const float* __restrict__ features,
                                               ushort_t* FB, int tid) {
#pragma unroll
    for (int it = 0; it < 8; ++it) {
        int bid = tid + it * 256;            // 0..2047
        int cb = bid & 15;
        int qb = (bid >> 4) & 3;
        int nt = (bid >> 6) & 7;
        int kt = bid >> 9;
        int m  = nt * 16 + cb;
        int d0 = kt * 32 + qb * 8;
        const float* fp = features + d0 * M_ + m;
        ushort8 u;
#pragma unroll
        for (int j = 0; j < 8; ++j) u[j] = f2bf(fp[j * M_]);
        *(ushort8*)(FB + bid * 8) = u;
    }
}

// Kernel A: per (chunk,b): phi_k = relu(K^T F)*s ; kv_part[m][v] += phi^T V^T ; ksum partials
// NCHUNK=32 -> grid 512 -> 2 blocks/CU resident (LDS 64KB x2 = 128KB <= 160KB)
__global__ __launch_bounds__(256) void kernelA(const float* __restrict__ keys,
                                               const float* __restrict__ values,
                                               const float* __restrict__ features,
                                               float* __restrict__ kvp,
                                               float* __restrict__ ksum_p) {
    __shared__ ushort_t FB[16384];  // 32 KB : F B-frags
    __shared__ ushort_t PA[8192];   // 16 KB : phi^T A-frags (64 l x 128 m)
    __shared__ ushort_t VB[8192];   // 16 KB : V B-frags   (64 l x 128 v)

    const int tid = threadIdx.x;
    const int chunk = blockIdx.x, b = blockIdx.y;
    const int w = tid >> 6, lane = tid & 63;
    const int qa = lane >> 4, ra = lane & 15;

    stage_features(features, FB, tid);

    float4v acc2[2][8];
    float   ksum_acc[8];
#pragma unroll
    for (int i = 0; i < 2; ++i)
#pragma unroll
        for (int nt = 0; nt < 8; ++nt) acc2[i][nt] = (float4v){0.f, 0.f, 0.f, 0.f};
#pragma unroll
    for (int nt = 0; nt < 8; ++nt) ksum_acc[nt] = 0.f;

    const int l0 = chunk * LT;

    for (int s = 0; s < 4; ++s) {
        const int ls = l0 + s * SL;
        __syncthreads();  // prev GEMM2 done; PA/VB reusable; (s=0: FB visible)

        // ---- issue ALL V-stage loads first (one latency exposure)
        float4v f0[4], f1[4];
#pragma unroll
        for (int it = 0; it < 4; ++it) {
            int bid = tid + it * 256;        // 0..1023
            int cb = bid & 15;
            int qb = (bid >> 4) & 3;
            int nt = (bid >> 6) & 7;
            int kt = bid >> 9;               // 0..1
            int v  = nt * 16 + cb;
            int lr = kt * 32 + qb * 8;
            const float* vp = values + ((size_t)(b * D_ + v)) * L_ + ls + lr;
            f0[it] = *(const float4v*)vp;
            f1[it] = *(const float4v*)(vp + 4);
        }

        // ---- issue ALL K-gather loads for GEMM1 (batched, overlaps V latency)
        ushort8 af[4];
        const int l = ls + w * 16 + ra;
        const float* kb_ = keys + (size_t)b * D_ * L_ + l;
#pragma unroll
        for (int kt = 0; kt < 4; ++kt) {
            const float* kp = kb_ + (size_t)(kt * 32 + qa * 8) * L_;
            ushort8 a;
#pragma unroll
            for (int j = 0; j < 8; ++j) a[j] = f2bf(kp[(size_t)j * L_]);
            af[kt] = a;
        }

        // ---- write V subtile to LDS (B-frag layout B[k=l_rel][n=v])
#pragma unroll
        for (int it = 0; it < 4; ++it) {
            int bid = tid + it * 256;
            ushort8 u;
            u[0] = f2bf(f0[it].x); u[1] = f2bf(f0[it].y); u[2] = f2bf(f0[it].z); u[3] = f2bf(f0[it].w);
            u[4] = f2bf(f1[it].x); u[5] = f2bf(f1[it].y); u[6] = f2bf(f1[it].z); u[7] = f2bf(f1[it].w);
            *(ushort8*)(VB + bid * 8) = u;
        }

        // ---- GEMM1: phi(64 x 128) = K_sub^T (64 x 128) @ F(128 x 128); wave w owns l-rows [w*16, w*16+16)
        float4v acc1[8];
#pragma unroll
        for (int nt = 0; nt < 8; ++nt) acc1[nt] = (float4v){0.f, 0.f, 0.f, 0.f};
#pragma unroll
        for (int kt = 0; kt < 4; ++kt)
#pragma unroll
            for (int nt = 0; nt < 8; ++nt)
                acc1[nt] = mfma16(af[kt], *(const ushort8*)(FB + ((kt * 8 + nt) * 64 + lane) * 8),
                                  acc1[nt]);

        // ---- epilogue: relu*scale, ksum accumulate, write phi^T into A-frag layout (b64 packed)
        {
            const int qc = qa, cc = ra;
            const int kt2 = w >> 1;
            const int qa2 = (w & 1) * 2 + (qc >> 1);
            const int jb  = (qc & 1) * 4;
#pragma unroll
            for (int nt = 0; nt < 8; ++nt) {
                float4v p = acc1[nt];
                p.x = fmaxf(p.x, 0.f) * PHI_SCALE;
                p.y = fmaxf(p.y, 0.f) * PHI_SCALE;
                p.z = fmaxf(p.z, 0.f) * PHI_SCALE;
                p.w = fmaxf(p.w, 0.f) * PHI_SCALE;
                ksum_acc[nt] += p.x + p.y + p.z + p.w;
                ushort4v u4 = {f2bf(p.x), f2bf(p.y), f2bf(p.z), f2bf(p.w)};
                *(ushort4v*)(PA + (((kt2 * 8 + nt) * 64 + qa2 * 16 + cc) * 8 + jb)) = u4;
            }
        }
        __syncthreads();  // PA + VB visible

        // ---- GEMM2: kv[m][v] += phi^T (128 x 64) @ V (64 x 128); wave w owns m-rows [32w,32w+32)
#pragma unroll
        for (int kt2 = 0; kt2 < 2; ++kt2) {
            ushort8 a0 = *(const ushort8*)(PA + ((kt2 * 8 + 2 * w + 0) * 64 + lane) * 8);
            ushort8 a1 = *(const ushort8*)(PA + ((kt2 * 8 + 2 * w + 1) * 64 + lane) * 8);
#pragma unroll
            for (int nt = 0; nt < 8; ++nt) {
                ushort8 bb = *(const ushort8*)(VB + ((kt2 * 8 + nt) * 64 + lane) * 8);
                acc2[0][nt] = mfma16(a0, bb, acc2[0][nt]);
                acc2[1][nt] = mfma16(a1, bb, acc2[1][nt]);
            }
        }
    }

    // ---- write kv partials (f32) and ksum partials
    float* kvpb = kvp + ((size_t)(b * NCHUNK + chunk)) * M_ * D_;
    const int qc = lane >> 4, cc = lane & 15;
#pragma unroll
    for (int mi = 0; mi < 2; ++mi)
#pragma unroll
        for (int nt = 0; nt < 8; ++nt) {
            float4v p = acc2[mi][nt];
            int m0 = w * 32 + mi * 16 + qc * 4;
            int v  = nt * 16 + cc;
            kvpb[(m0 + 0) * D_ + v] = p.x;
            kvpb[(m0 + 1) * D_ + v] = p.y;
            kvpb[(m0 + 2) * D_ + v] = p.z;
            kvpb[(m0 + 3) * D_ + v] = p.w;
        }
    float* ksb = ksum_p + ((size_t)((b * NCHUNK + chunk) * 4 + w)) * M_;
#pragma unroll
    for (int nt = 0; nt < 8; ++nt) {
        float sv = ksum_acc[nt];
        sv += __shfl_xor(sv, 16);
        sv += __shfl_xor(sv, 32);
        if (qc == 0) ksb[nt * 16 + cc] = sv;  // m = nt*16+cc, summed over this wave's l rows
    }
}

// Kernel R: reduce 32 chunk-partials -> kv_final (128 x 128 bf16 B-frag blocks
// [kt 0..3][nt 0..7][lane64][j]) + ksum_final f32 [b][128]
__global__ __launch_bounds__(256) void kernelR(const float* __restrict__ kvp,
                                               const float* __restrict__ ksum_p,
                                               ushort_t* __restrict__ kv_final,
                                               float* __restrict__ ksum_final) {
    if (blockIdx.x < 128) {
        int t = blockIdx.x * 256 + threadIdx.x;  // 0..32767
        int b = t >> 11, bid = t & 2047;
        int cb = bid & 15, qb = (bid >> 4) & 3, nt = (bid >> 6) & 7, kt = bid >> 9;
        int v  = nt * 16 + cb;
        int m0 = kt * 32 + qb * 8;
        const float* base = kvp + ((size_t)b * NCHUNK) * (M_ * D_) + m0 * D_ + v;
        float sacc[8];
#pragma unroll
        for (int j = 0; j < 8; ++j) sacc[j] = 0.f;
#pragma unroll 4
        for (int c = 0; c < NCHUNK; ++c) {
            const float* p = base + (size_t)c * (M_ * D_);
#pragma unroll
            for (int j = 0; j < 8; ++j) sacc[j] += p[j * D_];
        }
        ushort8 u;
#pragma unroll
        for (int j = 0; j < 8; ++j) u[j] = f2bf(sacc[j]);
        *(ushort8*)(kv_final + (size_t)t * 8) = u;
    } else {
        int t2 = (blockIdx.x - 128) * 256 + threadIdx.x;  // 0..2047
        int b = t2 >> 7, m = t2 & 127;
        const float* p = ksum_p + ((size_t)b * NCHUNK) * 4 * M_ + m;
        float sacc = 0.f;
#pragma unroll 8
        for (int cw = 0; cw < NCHUNK * 4; ++cw) sacc += p[cw * M_];
        ksum_final[t2] = sacc;
    }
}

// Kernel QC (fused): phi_q = relu(Q^T F)*s in registers ; out = (phi_q @ kv)/(phi_q . ksum)
// C-frag -> A-frag transpose is INTRA-WAVE via per-wave-private 4KB PQA block -> no barriers
// in the main loop. LDS = 32+32+16 KB = 81920 B -> 2 blocks/CU (exact 160KB fit).
__global__ __launch_bounds__(256) void kernelQC(const float* __restrict__ queries,
                                                const float* __restrict__ features,
                                                const ushort_t* __restrict__ kv_final,
                                                const float* __restrict__ ksum_final,
                                                float* __restrict__ out) {
    __shared__ ushort_t FB[16384];   // 32 KB : F B-frags
    __shared__ ushort_t KVB[16384];  // 32 KB : kv B-frags (B[k=m][n=v])
    __shared__ ushort_t PQA[8192];   // 16 KB : phi_q A-frags, per-wave-private blocks

    const int tid = threadIdx.x;
    const int chunk = blockIdx.x, b = blockIdx.y;
    const int w = tid >> 6, lane = tid & 63;
    const int qa = lane >> 4, ra = lane & 15;

    stage_features(features, FB, tid);
#pragma unroll
    for (int it = 0; it < 8; ++it) {
        int bid = tid + it * 256;  // 0..2047
        *(ushort8*)(KVB + bid * 8) =
            *(const ushort8*)(kv_final + ((size_t)b * 2048 + bid) * 8);
    }
    // ksum in registers: lane (qc,cc) needs ksum[m = nt*16+cc]
    float ks[8];
#pragma unroll
    for (int nt = 0; nt < 8; ++nt) ks[nt] = ksum_final[b * M_ + nt * 16 + ra];
    __syncthreads();

    for (int s = 0; s < 4; ++s) {
        const int ls = chunk * LT + s * SL;
        const int l = ls + w * 16 + ra;

        // ---- GEMM1: batched Q gather (32 loads in flight), then MFMAs
        ushort8 af[4];
        const float* qb_ = queries + (size_t)b * D_ * L_ + l;
#pragma unroll
        for (int kt = 0; kt < 4; ++kt) {
            const float* qp = qb_ + (size_t)(kt * 32 + qa * 8) * L_;
            ushort8 a;
#pragma unroll
            for (int j = 0; j < 8; ++j) a[j] = f2bf(qp[(size_t)j * L_]);
            af[kt] = a;
        }
        float4v acc1[8];
#pragma unroll
        for (int nt = 0; nt < 8; ++nt) acc1[nt] = (float4v){0.f, 0.f, 0.f, 0.f};
#pragma unroll
        for (int kt = 0; kt < 4; ++kt)
#pragma unroll
            for (int nt = 0; nt < 8; ++nt)
                acc1[nt] = mfma16(af[kt], *(const ushort8*)(FB + ((kt * 8 + nt) * 64 + lane) * 8),
                                  acc1[nt]);

        // ---- epilogue: relu*scale, f32 denominator dot, write phi_q to own PQA block
        const int qc = qa, cc = ra;
        float dp0 = 0.f, dp1 = 0.f, dp2 = 0.f, dp3 = 0.f;
#pragma unroll
        for (int nt = 0; nt < 8; ++nt) {
            float4v p = acc1[nt];
            p.x = fmaxf(p.x, 0.f) * PHI_SCALE;
            p.y = fmaxf(p.y, 0.f) * PHI_SCALE;
            p.z = fmaxf(p.z, 0.f) * PHI_SCALE;
            p.w = fmaxf(p.w, 0.f) * PHI_SCALE;
            dp0 += p.x * ks[nt]; dp1 += p.y * ks[nt];
            dp2 += p.z * ks[nt]; dp3 += p.w * ks[nt];
            // (l_rel = w*16+qc*4+r, m = nt*16+cc) -> A-frag [kt=nt>>1][lt=w][qa'=(nt&1)*2+(cc>>3)][ra'=qc*4+r][j=cc&7]
            int baseaddr = ((((nt >> 1) * 4 + w) * 64 + ((nt & 1) * 2 + (cc >> 3)) * 16 + qc * 4) * 8) + (cc & 7);
            PQA[baseaddr +  0] = f2bf(p.x);
            PQA[baseaddr +  8] = f2bf(p.y);
            PQA[baseaddr + 16] = f2bf(p.z);
            PQA[baseaddr + 24] = f2bf(p.w);
        }
        // reduce denom over the 16 cc-lanes (lane bits 0..3)
#pragma unroll
        for (int off = 1; off < 16; off <<= 1) {
            dp0 += __shfl_xor(dp0, off);
            dp1 += __shfl_xor(dp1, off);
            dp2 += __shfl_xor(dp2, off);
            dp3 += __shfl_xor(dp3, off);
        }
        float i0 = 1.f / dp0, i1 = 1.f / dp1, i2 = 1.f / dp2, i3 = 1.f / dp3;

        // ---- GEMM2: out(64 l x 128 v) = phi_q(64 x 128) @ kv(128 x 128); intra-wave PQA read
        float4v acc[8];
#pragma unroll
        for (int nt = 0; nt < 8; ++nt) acc[nt] = (float4v){0.f, 0.f, 0.f, 0.f};
#pragma unroll
        for (int kt = 0; kt < 4; ++kt) {
            ushort8 a = *(const ushort8*)(PQA + ((kt * 4 + w) * 64 + lane) * 8);
#pragma unroll
            for (int nt = 0; nt < 8; ++nt)
                acc[nt] = mfma16(a, *(const ushort8*)(KVB + ((kt * 8 + nt) * 64 + lane) * 8),
                                 acc[nt]);
        }
        const int lbase = ls + w * 16 + qc * 4;
#pragma unroll
        for (int nt = 0; nt < 8; ++nt) {
            float4v o = acc[nt];
            o.x *= i0; o.y *= i1; o.z *= i2; o.w *= i3;
            *(float4v*)(out + ((size_t)(b * D_ + nt * 16 + cc)) * L_ + lbase) = o;
        }
    }
}

extern "C" void kernel_launch(void* const* d_in, const int* in_sizes, int n_in,
                              void* d_out, int out_size, void* d_ws, size_t ws_size,
                              hipStream_t stream) {
    (void)in_sizes; (void)n_in; (void)out_size; (void)ws_size;
    const float* keys     = (const float*)d_in[0];
    const float* values   = (const float*)d_in[1];
    const float* queries  = (const float*)d_in[2];
    const float* features = (const float*)d_in[3];
    float* out = (float*)d_out;

    // workspace partition (total ~35.1 MB)
    char* ws = (char*)d_ws;
    float*    kvp        = (float*)ws;                        // 16*32*128*128*4 = 33,554,432
    float*    ksum_p     = (float*)(ws + 33554432);           // 16*32*4*128*4   =  1,048,576
    ushort_t* kv_final   = (ushort_t*)(ws + 34603008);        // 16*2048*8*2     =    524,288
    float*    ksum_final = (float*)(ws + 35127296);           // 16*128*4        =      8,192

    dim3 grid(NCHUNK, B_);
    kernelA<<<grid, 256, 0, stream>>>(keys, values, features, kvp, ksum_p);
    kernelR<<<136, 256, 0, stream>>>(kvp, ksum_p, kv_final, ksum_final);
    kernelQC<<<grid, 256, 0, stream>>>(queries, features, kv_final, ksum_final, out);
}

// Round 2
// 266.883 us; speedup vs baseline: 1.1469x; 1.1035x over previous
//
#include <hip/hip_runtime.h>

#define B_ 16
#define D_ 128
#define L_ 8192
#define M_ 128
#define NCHUNK 32
#define LT 256
#define SL 64
#define PHI_SCALE 0.08838834764831845f

typedef unsigned short ushort_t;
typedef ushort_t ushort8 __attribute__((ext_vector_type(8)));
typedef ushort_t ushort4v __attribute__((ext_vector_type(4)));
typedef float float4v __attribute__((ext_vector_type(4)));
typedef __bf16 bf16x8 __attribute__((ext_vector_type(8)));

__device__ __forceinline__ ushort_t f2bf(float f) {
    unsigned int u = __builtin_bit_cast(unsigned int, f);
    unsigned int r = u + 0x7FFFu + ((u >> 16) & 1u);   // RTNE
    return (ushort_t)(r >> 16);
}

__device__ __forceinline__ float4v mfma16(ushort8 a, ushort8 b, float4v c) {
    return __builtin_amdgcn_mfma_f32_16x16x32_bf16(
        __builtin_bit_cast(bf16x8, a), __builtin_bit_cast(bf16x8, b), c, 0, 0, 0);
}

// Stage F (D x M) into LDS as GEMM B-fragment layout: blocks [kt 0..3][nt 0..7][lane64][j 0..7]
__device__ __forceinline__ void stage_features(const float* __restrict__ features,
                                               ushort_t* FB, int tid) {
#pragma unroll
    for (int it = 0; it < 8; ++it) {
        int bid = tid + it * 256;            // 0..2047
        int cb = bid & 15;
        int qb = (bid >> 4) & 3;
        int nt = (bid >> 6) & 7;
        int kt = bid >> 9;
        int m  = nt * 16 + cb;
        int d0 = kt * 32 + qb * 8;
        const float* fp = features + d0 * M_ + m;
        ushort8 u;
#pragma unroll
        for (int j = 0; j < 8; ++j) u[j] = f2bf(fp[j * M_]);
        *(ushort8*)(FB + bid * 8) = u;
    }
}

// Kernel A: per (chunk,b): phi_k = relu(K^T F)*s ; kv_part[m][v] += phi^T V^T ; ksum partials
// LDS 64KB -> 2 blocks/CU. Raw-f32 prefetch of next s-iter's K+V hides HBM latency under MFMA.
__global__ __launch_bounds__(256, 2) void kernelA(const float* __restrict__ keys,
                                                  const float* __restrict__ values,
                                                  const float* __restrict__ features,
                                                  float* __restrict__ kvp,
                                                  float* __restrict__ ksum_p) {
    __shared__ ushort_t FB[16384];  // 32 KB : F B-frags
    __shared__ ushort_t PA[8192];   // 16 KB : phi^T A-frags (64 l x 128 m)
    __shared__ ushort_t VB[8192];   // 16 KB : V B-frags   (64 l x 128 v)

    const int tid = threadIdx.x;
    const int chunk = blockIdx.x, b = blockIdx.y;
    const int w = tid >> 6, lane = tid & 63;
    const int qa = lane >> 4, ra = lane & 15;
    const int l0 = chunk * LT;
    const int lrel = w * 16 + ra;

    // per-it V addressing (invariant part)
    int v_off[4];
#pragma unroll
    for (int it = 0; it < 4; ++it) {
        int bid = tid + it * 256;
        int v  = ((bid >> 6) & 7) * 16 + (bid & 15);
        int lr = (bid >> 9) * 32 + ((bid >> 4) & 3) * 8;
        v_off[it] = (b * D_ + v) * L_ + lr;
    }
    const float* kcol = keys + (size_t)b * D_ * L_;

    // ---- issue s=0 V + K loads first (raw f32, converted at use)
    float4v vf[4][2];
    float   fk[4][8];
#pragma unroll
    for (int it = 0; it < 4; ++it) {
        const float* vp = values + v_off[it] + l0;
        vf[it][0] = *(const float4v*)vp;
        vf[it][1] = *(const float4v*)(vp + 4);
    }
#pragma unroll
    for (int kt = 0; kt < 4; ++kt)
#pragma unroll
        for (int j = 0; j < 8; ++j)
            fk[kt][j] = kcol[(size_t)(kt * 32 + qa * 8 + j) * L_ + l0 + lrel];

    stage_features(features, FB, tid);

    float4v acc2[2][8];
    float   ksum_acc[8];
#pragma unroll
    for (int i = 0; i < 2; ++i)
#pragma unroll
        for (int nt = 0; nt < 8; ++nt) acc2[i][nt] = (float4v){0.f, 0.f, 0.f, 0.f};
#pragma unroll
    for (int nt = 0; nt < 8; ++nt) ksum_acc[nt] = 0.f;

#pragma unroll
    for (int s = 0; s < 4; ++s) {
        const int ls = l0 + s * SL;
        __syncthreads();  // prev GEMM2 done; PA/VB reusable; (s=0: FB visible)

        // ---- write V subtile to LDS (consumes vf)
#pragma unroll
        for (int it = 0; it < 4; ++it) {
            ushort8 u;
            u[0] = f2bf(vf[it][0].x); u[1] = f2bf(vf[it][0].y);
            u[2] = f2bf(vf[it][0].z); u[3] = f2bf(vf[it][0].w);
            u[4] = f2bf(vf[it][1].x); u[5] = f2bf(vf[it][1].y);
            u[6] = f2bf(vf[it][1].z); u[7] = f2bf(vf[it][1].w);
            *(ushort8*)(VB + (tid + it * 256) * 8) = u;
        }

        // ---- convert K (consumes fk)
        ushort8 af[4];
#pragma unroll
        for (int kt = 0; kt < 4; ++kt) {
            ushort8 a;
#pragma unroll
            for (int j = 0; j < 8; ++j) a[j] = f2bf(fk[kt][j]);
            af[kt] = a;
        }

        // ---- prefetch next s-iter's V + K (in flight across GEMM1+epilogue+GEMM2)
        if (s < 3) {
#pragma unroll
            for (int it = 0; it < 4; ++it) {
                const float* vp = values + v_off[it] + ls + SL;
                vf[it][0] = *(const float4v*)vp;
                vf[it][1] = *(const float4v*)(vp + 4);
            }
#pragma unroll
            for (int kt = 0; kt < 4; ++kt)
#pragma unroll
                for (int j = 0; j < 8; ++j)
                    fk[kt][j] = kcol[(size_t)(kt * 32 + qa * 8 + j) * L_ + ls + SL + lrel];
        }

        // ---- GEMM1: phi(64 x 128) = K_sub^T @ F; wave w owns l-rows [w*16, w*16+16)
        float4v acc1[8];
#pragma unroll
        for (int nt = 0; nt < 8; ++nt) acc1[nt] = (float4v){0.f, 0.f, 0.f, 0.f};
#pragma unroll
        for (int kt = 0; kt < 4; ++kt)
#pragma unroll
            for (int nt = 0; nt < 8; ++nt)
                acc1[nt] = mfma16(af[kt], *(const ushort8*)(FB + ((kt * 8 + nt) * 64 + lane) * 8),
                                  acc1[nt]);

        // ---- epilogue: relu*scale, ksum accumulate, write phi^T into A-frag layout
        {
            const int qc = qa, cc = ra;
            const int kt2 = w >> 1;
            const int qa2 = (w & 1) * 2 + (qc >> 1);
            const int jb  = (qc & 1) * 4;
#pragma unroll
            for (int nt = 0; nt < 8; ++nt) {
                float4v p = acc1[nt];
                p.x = fmaxf(p.x, 0.f) * PHI_SCALE;
                p.y = fmaxf(p.y, 0.f) * PHI_SCALE;
                p.z = fmaxf(p.z, 0.f) * PHI_SCALE;
                p.w = fmaxf(p.w, 0.f) * PHI_SCALE;
                ksum_acc[nt] += p.x + p.y + p.z + p.w;
                ushort4v u4 = {f2bf(p.x), f2bf(p.y), f2bf(p.z), f2bf(p.w)};
                *(ushort4v*)(PA + (((kt2 * 8 + nt) * 64 + qa2 * 16 + cc) * 8 + jb)) = u4;
            }
        }
        __syncthreads();  // PA + VB visible

        // ---- GEMM2: kv[m][v] += phi^T (128 x 64) @ V (64 x 128); wave w owns m-rows [32w,32w+32)
#pragma unroll
        for (int kt2 = 0; kt2 < 2; ++kt2) {
            ushort8 a0 = *(const ushort8*)(PA + ((kt2 * 8 + 2 * w + 0) * 64 + lane) * 8);
            ushort8 a1 = *(const ushort8*)(PA + ((kt2 * 8 + 2 * w + 1) * 64 + lane) * 8);
#pragma unroll
            for (int nt = 0; nt < 8; ++nt) {
                ushort8 bb = *(const ushort8*)(VB + ((kt2 * 8 + nt) * 64 + lane) * 8);
                acc2[0][nt] = mfma16(a0, bb, acc2[0][nt]);
                acc2[1][nt] = mfma16(a1, bb, acc2[1][nt]);
            }
        }
    }

    // ---- write kv partials (f32) and ksum partials
    float* kvpb = kvp + ((size_t)(b * NCHUNK + chunk)) * M_ * D_;
    const int qc = lane >> 4, cc = lane & 15;
#pragma unroll
    for (int mi = 0; mi < 2; ++mi)
#pragma unroll
        for (int nt = 0; nt < 8; ++nt) {
            float4v p = acc2[mi][nt];
            int m0 = w * 32 + mi * 16 + qc * 4;
            int v  = nt * 16 + cc;
            kvpb[(m0 + 0) * D_ + v] = p.x;
            kvpb[(m0 + 1) * D_ + v] = p.y;
            kvpb[(m0 + 2) * D_ + v] = p.z;
            kvpb[(m0 + 3) * D_ + v] = p.w;
        }
    float* ksb = ksum_p + ((size_t)((b * NCHUNK + chunk) * 4 + w)) * M_;
#pragma unroll
    for (int nt = 0; nt < 8; ++nt) {
        float sv = ksum_acc[nt];
        sv += __shfl_xor(sv, 16);
        sv += __shfl_xor(sv, 32);
        if (qc == 0) ksb[nt * 16 + cc] = sv;
    }
}

// Kernel R: reduce 32 chunk-partials -> kv_final (bf16 B-frag blocks) + ksum_final f32 [b][128]
// 264 blocks: kv slots split in j-halves across block pairs for better CU coverage.
__global__ __launch_bounds__(256) void kernelR(const float* __restrict__ kvp,
                                               const float* __restrict__ ksum_p,
                                               ushort_t* __restrict__ kv_final,
                                               float* __restrict__ ksum_final) {
    if (blockIdx.x < 256) {
        int h = blockIdx.x >> 7;                       // j-half 0/1
        int t = (blockIdx.x & 127) * 256 + threadIdx.x;  // slot 0..32767
        int b = t >> 11, bid = t & 2047;
        int cb = bid & 15, qb = (bid >> 4) & 3, nt = (bid >> 6) & 7, kt = bid >> 9;
        int v  = nt * 16 + cb;
        int m0 = kt * 32 + qb * 8 + h * 4;
        const float* base = kvp + ((size_t)b * NCHUNK) * (M_ * D_) + m0 * D_ + v;
        float s0 = 0.f, s1 = 0.f, s2 = 0.f, s3 = 0.f;
#pragma unroll 4
        for (int c = 0; c < NCHUNK; ++c) {
            const float* p = base + (size_t)c * (M_ * D_);
            s0 += p[0 * D_]; s1 += p[1 * D_]; s2 += p[2 * D_]; s3 += p[3 * D_];
        }
        ushort4v u = {f2bf(s0), f2bf(s1), f2bf(s2), f2bf(s3)};
        *(ushort4v*)(kv_final + (size_t)t * 8 + h * 4) = u;
    } else {
        int t2 = (blockIdx.x - 256) * 256 + threadIdx.x;  // 0..2047
        int b = t2 >> 7, m = t2 & 127;
        const float* p = ksum_p + ((size_t)b * NCHUNK) * 4 * M_ + m;
        float sacc = 0.f;
#pragma unroll 8
        for (int cw = 0; cw < NCHUNK * 4; ++cw) sacc += p[cw * M_];
        ksum_final[t2] = sacc;
    }
}

// Kernel QC (fused): phi_q = relu(Q^T F)*s ; out = (phi_q @ kv)/(phi_q . ksum)
// LDS = 32+32+8 = 72 KB -> 2 blocks/CU. PQA halved: nt 0..3 -> GEMM2 kt 0,1 -> nt 4..7 ->
// kt 2,3 (per-wave-private, in-wave ordering only). Raw-f32 Q prefetch pipelines s-iters.
__global__ __launch_bounds__(256, 2) void kernelQC(const float* __restrict__ queries,
                                                   const float* __restrict__ features,
                                                   const ushort_t* __restrict__ kv_final,
                                                   const float* __restrict__ ksum_final,
                                                   float* __restrict__ out) {
    __shared__ ushort_t FB[16384];   // 32 KB : F B-frags
    __shared__ ushort_t KVB[16384];  // 32 KB : kv B-frags (B[k=m][n=v])
    __shared__ ushort_t PQA[4096];   //  8 KB : phi_q A-frags, per-wave halves

    const int tid = threadIdx.x;
    const int chunk = blockIdx.x, b = blockIdx.y;
    const int w = tid >> 6, lane = tid & 63;
    const int qa = lane >> 4, ra = lane & 15;
    const int qc = qa, cc = ra;
    const int lrel = w * 16 + ra;

    // ---- issue s=0 Q loads first (raw f32)
    const float* qbase = queries + (size_t)b * D_ * L_;
    float fq[4][8];
#pragma unroll
    for (int kt = 0; kt < 4; ++kt)
#pragma unroll
        for (int j = 0; j < 8; ++j)
            fq[kt][j] = qbase[(size_t)(kt * 32 + qa * 8 + j) * L_ + chunk * LT + lrel];

    stage_features(features, FB, tid);
#pragma unroll
    for (int it = 0; it < 8; ++it) {
        int bid = tid + it * 256;  // 0..2047
        *(ushort8*)(KVB + bid * 8) =
            *(const ushort8*)(kv_final + ((size_t)b * 2048 + bid) * 8);
    }
    float ks[8];
#pragma unroll
    for (int nt = 0; nt < 8; ++nt) ks[nt] = ksum_final[b * M_ + nt * 16 + ra];
    __syncthreads();

#pragma unroll
    for (int s = 0; s < 4; ++s) {
        const int ls = chunk * LT + s * SL;

        // ---- convert current Q (consumes fq)
        ushort8 af[4];
#pragma unroll
        for (int kt = 0; kt < 4; ++kt) {
            ushort8 a;
#pragma unroll
            for (int j = 0; j < 8; ++j) a[j] = f2bf(fq[kt][j]);
            af[kt] = a;
        }
        // ---- prefetch next s-iter's Q
        if (s < 3) {
#pragma unroll
            for (int kt = 0; kt < 4; ++kt)
#pragma unroll
                for (int j = 0; j < 8; ++j)
                    fq[kt][j] = qbase[(size_t)(kt * 32 + qa * 8 + j) * L_ + ls + SL + lrel];
        }

        // ---- GEMM1: phi_q(64 x 128) = Q_sub^T @ F
        float4v acc1[8];
#pragma unroll
        for (int nt = 0; nt < 8; ++nt) acc1[nt] = (float4v){0.f, 0.f, 0.f, 0.f};
#pragma unroll
        for (int kt = 0; kt < 4; ++kt)
#pragma unroll
            for (int nt = 0; nt < 8; ++nt)
                acc1[nt] = mfma16(af[kt], *(const ushort8*)(FB + ((kt * 8 + nt) * 64 + lane) * 8),
                                  acc1[nt]);

        // ---- relu*scale + f32 denominator dot (ksum in regs)
        float dp0 = 0.f, dp1 = 0.f, dp2 = 0.f, dp3 = 0.f;
#pragma unroll
        for (int nt = 0; nt < 8; ++nt) {
            float4v p = acc1[nt];
            p.x = fmaxf(p.x, 0.f) * PHI_SCALE;
            p.y = fmaxf(p.y, 0.f) * PHI_SCALE;
            p.z = fmaxf(p.z, 0.f) * PHI_SCALE;
            p.w = fmaxf(p.w, 0.f) * PHI_SCALE;
            dp0 += p.x * ks[nt]; dp1 += p.y * ks[nt];
            dp2 += p.z * ks[nt]; dp3 += p.w * ks[nt];
            acc1[nt] = p;
        }
#pragma unroll
        for (int off = 1; off < 16; off <<= 1) {
            dp0 += __shfl_xor(dp0, off);
            dp1 += __shfl_xor(dp1, off);
            dp2 += __shfl_xor(dp2, off);
            dp3 += __shfl_xor(dp3, off);
        }
        float i0 = 1.f / dp0, i1 = 1.f / dp1, i2 = 1.f / dp2, i3 = 1.f / dp3;

        // ---- GEMM2 in two m-halves through the 8KB per-wave PQA
        float4v acc[8];
#pragma unroll
        for (int nt = 0; nt < 8; ++nt) acc[nt] = (float4v){0.f, 0.f, 0.f, 0.f};
#pragma unroll
        for (int h = 0; h < 2; ++h) {
#pragma unroll
            for (int nt = 4 * h; nt < 4 * h + 4; ++nt) {
                float4v p = acc1[nt];
                // (l_rel=w*16+qc*4+r, m=nt*16+cc) -> A-frag block ((nt>>1)&1)*4+w
                int baseu = ((((nt >> 1) & 1) * 4 + w) * 64 +
                             ((nt & 1) * 2 + (cc >> 3)) * 16 + qc * 4) * 8 + (cc & 7);
                PQA[baseu +  0] = f2bf(p.x);
                PQA[baseu +  8] = f2bf(p.y);
                PQA[baseu + 16] = f2bf(p.z);
                PQA[baseu + 24] = f2bf(p.w);
            }
#pragma unroll
            for (int kt = 2 * h; kt < 2 * h + 2; ++kt) {
                ushort8 a = *(const ushort8*)(PQA + (((kt & 1) * 4 + w) * 64 + lane) * 8);
#pragma unroll
                for (int nt2 = 0; nt2 < 8; ++nt2)
                    acc[nt2] = mfma16(a, *(const ushort8*)(KVB + ((kt * 8 + nt2) * 64 + lane) * 8),
                                      acc[nt2]);
            }
        }

        // ---- scale by 1/denom and store
        const int lbase = ls + w * 16 + qc * 4;
#pragma unroll
        for (int nt = 0; nt < 8; ++nt) {
            float4v o = acc[nt];
            o.x *= i0; o.y *= i1; o.z *= i2; o.w *= i3;
            *(float4v*)(out + ((size_t)(b * D_ + nt * 16 + cc)) * L_ + lbase) = o;
        }
    }
}

extern "C" void kernel_launch(void* const* d_in, const int* in_sizes, int n_in,
                              void* d_out, int out_size, void* d_ws, size_t ws_size,
                              hipStream_t stream) {
    (void)in_sizes; (void)n_in; (void)out_size; (void)ws_size;
    const float* keys     = (const float*)d_in[0];
    const float* values   = (const float*)d_in[1];
    const float* queries  = (const float*)d_in[2];
    const float* features = (const float*)d_in[3];
    float* out = (float*)d_out;

    // workspace partition (total ~35.1 MB)
    char* ws = (char*)d_ws;
    float*    kvp        = (float*)ws;                        // 16*32*128*128*4 = 33,554,432
    float*    ksum_p     = (float*)(ws + 33554432);           // 16*32*4*128*4   =  1,048,576
    ushort_t* kv_final   = (ushort_t*)(ws + 34603008);        // 16*2048*8*2     =    524,288
    float*    ksum_final = (float*)(ws + 35127296);           // 16*128*4        =      8,192

    dim3 grid(NCHUNK, B_);
    kernelA<<<grid, 256, 0, stream>>>(keys, values, features, kvp, ksum_p);
    kernelR<<<264, 256, 0, stream>>>(kvp, ksum_p, kv_final, ksum_final);
    kernelQC<<<grid, 256, 0, stream>>>(queries, features, kv_final, ksum_final, out);
}